// Round 1
// baseline (159.705 us; speedup 1.0000x reference)
//
#include <hip/hip_runtime.h>

typedef unsigned short u16;
typedef __attribute__((ext_vector_type(4))) float f32x4;
typedef __attribute__((ext_vector_type(8))) short short8;
typedef __attribute__((ext_vector_type(8))) __bf16 bf16x8;
typedef __attribute__((ext_vector_type(4))) unsigned short u16x4;

#define BATCH 16384
#define NINP 256
#define HID 1024
#define NOUT 16

// ---------- helpers ----------
__device__ __forceinline__ u16 f2bf(float f) {
  unsigned u = __builtin_bit_cast(unsigned, f);
  u += 0x7FFFu + ((u >> 16) & 1u);   // round-to-nearest-even
  return (u16)(u >> 16);
}
__device__ __forceinline__ float bf2f(u16 h) {
  return __builtin_bit_cast(float, ((unsigned)h) << 16);
}
__device__ __forceinline__ f32x4 mfma_bf16(short8 a, short8 b, f32x4 c) {
  return __builtin_amdgcn_mfma_f32_16x16x32_bf16(
      __builtin_bit_cast(bf16x8, a), __builtin_bit_cast(bf16x8, b), c, 0, 0, 0);
}
__device__ __forceinline__ void gload_lds16(const void* g, void* l) {
  __builtin_amdgcn_global_load_lds(
      (const __attribute__((address_space(1))) void*)g,
      (__attribute__((address_space(3))) void*)l, 16, 0, 0);
}

// ---------- workspace layout (bytes) ----------
static const size_t OFF_XB   = 0;          //  8,388,608  x bf16 [16384][256]
static const size_t OFF_H0   = 8388608;    // 33,554,432  H0 bf16 [16384][1024]
static const size_t OFF_H1   = 41943040;   // 33,554,432  H1 bf16
static const size_t OFF_W0T  = 75497472;   //    524,288  W0^T bf16 [1024][256]
static const size_t OFF_W1T  = 76021760;   //  2,097,152  W1^T bf16 [1024][1024]
static const size_t OFF_W2T  = 78118912;   //     32,768  W2^T bf16 [16][1024]
static const size_t OFF_UW2T = 78151680;   //    524,288  uw2t bf16 [256][32 o][32 f]
static const size_t OFF_UW3T = 78675968;   //    262,144  uw3t bf16 [256][16 o2][32 o]
static const size_t OFF_CB   = 78938112;   //         64  cb f32 [16] = b2 + sum_i ub3
static const size_t OFF_PART = 78938368;   //  4,194,304  part f32 [4][16384][16]

// ---------- fused elementwise converts ----------
__global__ __launch_bounds__(256) void k_convert(
    const float* __restrict__ x, const float* __restrict__ uw2,
    const float* __restrict__ uw3, const float* __restrict__ b2,
    const float* __restrict__ ub3,
    u16* __restrict__ xb, u16* __restrict__ uw2t, u16* __restrict__ uw3t,
    float* __restrict__ cb)
{
  const int bid = blockIdx.x;
  if (bid < 4096) {                       // x -> bf16, 4 elems/thread
    const int idx = (bid * 256 + threadIdx.x) * 4;
    const float4 v = *(const float4*)&x[idx];
    u16x4 o4 = { f2bf(v.x), f2bf(v.y), f2bf(v.z), f2bf(v.w) };
    *(u16x4*)&xb[idx] = o4;
  } else if (bid < 4352) {                // uw2t[i][o][f] = uw2[i][f][o]
    const int e = ((bid - 4096) * 256 + threadIdx.x) * 4;
    const float4 v = *(const float4*)&uw2[e];
    const int i = e >> 10, f = (e >> 5) & 31, o = e & 31;
    u16* d = &uw2t[i * 1024 + o * 32 + f];
    d[0] = f2bf(v.x); d[32] = f2bf(v.y); d[64] = f2bf(v.z); d[96] = f2bf(v.w);
  } else if (bid < 4480) {                // uw3t[i][o2][f] = uw3[i][f][o2]
    const int e = ((bid - 4352) * 256 + threadIdx.x) * 4;
    const float4 v = *(const float4*)&uw3[e];
    const int i = e >> 9, f = (e >> 4) & 31, o2 = e & 15;
    u16* d = &uw3t[i * 512 + o2 * 32 + f];
    d[0] = f2bf(v.x); d[32] = f2bf(v.y); d[64] = f2bf(v.z); d[96] = f2bf(v.w);
  } else {                                // cb[o] = b2[o] + sum_i ub3[i][o]
    const int t = threadIdx.x;
    if (t < 16) {
      float s = b2[t];
      for (int i = 0; i < 256; ++i) s += ub3[i * 16 + t];
      cb[t] = s;
    }
  }
}

// ---------- LDS-tiled transpose f32 [K][N] -> bf16 [N][K], all 3 weights ----------
__global__ __launch_bounds__(256) void k_transpose(
    const float* __restrict__ W0, const float* __restrict__ W1,
    const float* __restrict__ W2,
    u16* __restrict__ W0T, u16* __restrict__ W1T, u16* __restrict__ W2T)
{
  __shared__ float tile[32][33];
  const int bid = blockIdx.x;
  const float* src; u16* dst; int K, N, kb, ob;
  if (bid < 256)       { src = W0; dst = W0T; K = 256;  N = 1024; int t = bid;        kb = (t & 7) * 32;  ob = (t >> 3) * 32; }
  else if (bid < 1280) { src = W1; dst = W1T; K = 1024; N = 1024; int t = bid - 256;  kb = (t & 31) * 32; ob = (t >> 5) * 32; }
  else                 { src = W2; dst = W2T; K = 1024; N = 16;   int t = bid - 1280; kb = t * 32;        ob = 0; }
  const int tx = threadIdx.x & 31, ty = threadIdx.x >> 5;
  for (int r = ty; r < 32; r += 8)
    if (ob + tx < N) tile[r][tx] = src[(size_t)(kb + r) * N + ob + tx];
  __syncthreads();
  for (int r = ty; r < 32; r += 8)
    if (ob + r < N) dst[(size_t)(ob + r) * K + kb + tx] = f2bf(tile[tx][r]);
}

// ---------- MFMA GEMM: C = relu(A @ B^T + bias), bf16 in/out, fp32 acc ----------
// A [M][K] bf16, BT [N][K] bf16, C [M][N] bf16.  128x128 tile, BK=32, 4 waves 2x2.
__global__ __launch_bounds__(256, 2) void k_gemm(
    const u16* __restrict__ A, const u16* __restrict__ BT,
    const float* __restrict__ bias, u16* __restrict__ C,
    int M, int N, int K)
{
  const int tid = threadIdx.x;
  const int lane = tid & 63, wid = tid >> 6;
  const int l15 = lane & 15, g = lane >> 4;
  const int nbn = N >> 7;
  const int nwg = gridDim.x;
  int logical = blockIdx.x;
  if ((nwg & 7) == 0) {                       // bijective XCD swizzle
    const int q = nwg >> 3;
    logical = (logical & 7) * q + (logical >> 3);
  }
  const int bm = logical / nbn, bn = logical % nbn;
  const size_t rb = (size_t)bm * 128, cbase = (size_t)bn * 128;

  __shared__ __align__(16) u16 As[128 * 32];
  __shared__ __align__(16) u16 Bs[128 * 32];

  const int wr = (wid >> 1) * 64, wc = (wid & 1) * 64;
  f32x4 acc[4][4] = {};

  for (int kt = 0; kt < K; kt += 32) {
#pragma unroll
    for (int it = 0; it < 2; ++it) {
      const int s = it * 256 + tid;
      const int row = s >> 2, kc = s & 3;
      gload_lds16(&A[(rb + row) * K + kt + kc * 8], &As[s * 8]);
      gload_lds16(&BT[(cbase + row) * K + kt + kc * 8], &Bs[s * 8]);
    }
    __syncthreads();   // drains vmcnt before barrier (compiler-inserted)
    short8 a[4], b[4];
#pragma unroll
    for (int m = 0; m < 4; ++m)
      a[m] = *(const short8*)&As[(wr + m * 16 + l15) * 32 + g * 8];
#pragma unroll
    for (int n = 0; n < 4; ++n)
      b[n] = *(const short8*)&Bs[(wc + n * 16 + l15) * 32 + g * 8];
#pragma unroll
    for (int m = 0; m < 4; ++m)
#pragma unroll
      for (int n = 0; n < 4; ++n)
        acc[m][n] = mfma_bf16(a[m], b[n], acc[m][n]);
    __syncthreads();
  }

#pragma unroll
  for (int n = 0; n < 4; ++n) {
    const int col = (int)cbase + wc + n * 16 + l15;
    const float bv = bias[col];
#pragma unroll
    for (int m = 0; m < 4; ++m) {
#pragma unroll
      for (int r = 0; r < 4; ++r) {
        const int row = (int)rb + wr + m * 16 + g * 4 + r;
        float v = acc[m][n][r] + bv;
        v = fmaxf(v, 0.f);
        C[(size_t)row * N + col] = f2bf(v);
      }
    }
  }
}

// ---------- uni MLPs + final layer (H1 @ W2^T), partial over 4 chunks ----------
// grid = 1024: blockIdx = rowblk*4 + chunk. Block = 4 waves x 16 batch rows.
// chunk owns features i in [64c, 64c+64) and K-range [256c, 256c+256) of H1@W2.
__global__ __launch_bounds__(256) void k_uni(
    const float* __restrict__ x,
    const float* __restrict__ uw1, const float* __restrict__ ub1,
    const u16* __restrict__ uw2t, const float* __restrict__ ub2,
    const u16* __restrict__ uw3t,
    const u16* __restrict__ H1, const u16* __restrict__ W2T,
    float* __restrict__ part)
{
  const int tid = threadIdx.x, lane = tid & 63, wid = tid >> 6;
  const int l15 = lane & 15, g = lane >> 4;
  const int chunk = blockIdx.x & 3, rowblk = blockIdx.x >> 2;
  const int rb_blk = rowblk * 64;
  const int rb = rb_blk + wid * 16;
  const int i0 = chunk * 64;

  __shared__ __align__(16) u16 xt[64][68];      // x tile bf16, padded
  __shared__ __align__(16) u16 h2s[4][16][40];  // per-wave h2 bounce [b][o], padded

  {
    const int r0 = tid >> 4;
    const int c4 = (tid & 15) << 2;
#pragma unroll
    for (int rr = 0; rr < 64; rr += 16) {
      const float4 v = *(const float4*)&x[(size_t)(rb_blk + rr + r0) * NINP + i0 + c4];
      u16x4 o4 = { f2bf(v.x), f2bf(v.y), f2bf(v.z), f2bf(v.w) };
      *(u16x4*)&xt[rr + r0][c4] = o4;
    }
  }
  __syncthreads();

  f32x4 acc = {0.f, 0.f, 0.f, 0.f};
  const f32x4 zero4 = {0.f, 0.f, 0.f, 0.f};

  for (int ii = 0; ii < 64; ++ii) {
    const int i = i0 + ii;
    const float xv = bf2f(xt[wid * 16 + l15][ii]);

    // layer 1 (rank-1) in fp32, pack A-frag: h1[b=l15][f=8g+jj]
    const float4 w1lo = *(const float4*)&uw1[i * 32 + g * 8];
    const float4 w1hi = *(const float4*)&uw1[i * 32 + g * 8 + 4];
    const float4 b1lo = *(const float4*)&ub1[i * 32 + g * 8];
    const float4 b1hi = *(const float4*)&ub1[i * 32 + g * 8 + 4];
    short8 afrag;
    afrag[0] = (short)f2bf(fmaxf(xv * w1lo.x + b1lo.x, 0.f));
    afrag[1] = (short)f2bf(fmaxf(xv * w1lo.y + b1lo.y, 0.f));
    afrag[2] = (short)f2bf(fmaxf(xv * w1lo.z + b1lo.z, 0.f));
    afrag[3] = (short)f2bf(fmaxf(xv * w1lo.w + b1lo.w, 0.f));
    afrag[4] = (short)f2bf(fmaxf(xv * w1hi.x + b1hi.x, 0.f));
    afrag[5] = (short)f2bf(fmaxf(xv * w1hi.y + b1hi.y, 0.f));
    afrag[6] = (short)f2bf(fmaxf(xv * w1hi.z + b1hi.z, 0.f));
    afrag[7] = (short)f2bf(fmaxf(xv * w1hi.w + b1hi.w, 0.f));

    // layer 2: D2[b][o] = h1 @ uw2[i]; B[k=f][j=o] from uw2t[i][o][f]
    const short8 bv0 = *(const short8*)&uw2t[i * 1024 + l15 * 32 + g * 8];
    const short8 bv1 = *(const short8*)&uw2t[i * 1024 + (16 + l15) * 32 + g * 8];
    f32x4 d0 = mfma_bf16(afrag, bv0, zero4);
    f32x4 d1 = mfma_bf16(afrag, bv1, zero4);

    // h2 = relu(D2 + ub2[i]) -> LDS bounce (per-wave region)
    const float bb0 = ub2[i * 32 + l15];
    const float bb1 = ub2[i * 32 + 16 + l15];
#pragma unroll
    for (int r = 0; r < 4; ++r) {
      h2s[wid][g * 4 + r][l15]      = f2bf(fmaxf(d0[r] + bb0, 0.f));
      h2s[wid][g * 4 + r][16 + l15] = f2bf(fmaxf(d1[r] + bb1, 0.f));
    }
    // layer 3: acc[b][o2] += h2 @ uw3[i]; A from LDS (b128), B from uw3t[i][o2][o]
    const short8 a3 = *(const short8*)&h2s[wid][l15][g * 8];
    const short8 b3 = *(const short8*)&uw3t[i * 512 + l15 * 32 + g * 8];
    acc = mfma_bf16(a3, b3, acc);
  }

  // final layer K-chunk: acc[b][o2] += H1[b][kb..] @ W2T[o2][kb..]
  {
    const int kb0 = chunk * 256;
#pragma unroll
    for (int kk = 0; kk < 8; ++kk) {
      const int kb = kb0 + kk * 32;
      const short8 av = *(const short8*)&H1[(size_t)(rb + l15) * HID + kb + g * 8];
      const short8 bv = *(const short8*)&W2T[l15 * HID + kb + g * 8];
      acc = mfma_bf16(av, bv, acc);
    }
  }

  float* p = part + ((size_t)chunk * BATCH + rb) * NOUT;
#pragma unroll
  for (int r = 0; r < 4; ++r)
    p[(g * 4 + r) * NOUT + l15] = acc[r];
}

// ---------- reduce 4 partials + cb -> out ----------
__global__ __launch_bounds__(256) void k_reduce(
    const float* __restrict__ part, const float* __restrict__ cb,
    float* __restrict__ out)
{
  const int j4 = blockIdx.x * 256 + threadIdx.x;   // 65536 float4's
  const float4 c = ((const float4*)cb)[j4 & 3];
  const float4* p = (const float4*)part;
  const float4 a0 = p[j4], a1 = p[65536 + j4], a2 = p[131072 + j4], a3 = p[196608 + j4];
  float4 r;
  r.x = c.x + a0.x + a1.x + a2.x + a3.x;
  r.y = c.y + a0.y + a1.y + a2.y + a3.y;
  r.z = c.z + a0.z + a1.z + a2.z + a3.z;
  r.w = c.w + a0.w + a1.w + a2.w + a3.w;
  ((float4*)out)[j4] = r;
}

extern "C" void kernel_launch(void* const* d_in, const int* in_sizes, int n_in,
                              void* d_out, int out_size, void* d_ws, size_t ws_size,
                              hipStream_t stream) {
  (void)in_sizes; (void)n_in; (void)out_size; (void)ws_size;
  const float* x   = (const float*)d_in[0];
  const float* W0  = (const float*)d_in[1];
  const float* b0  = (const float*)d_in[2];
  const float* W1  = (const float*)d_in[3];
  const float* b1  = (const float*)d_in[4];
  const float* W2  = (const float*)d_in[5];
  const float* b2  = (const float*)d_in[6];
  const float* uw1 = (const float*)d_in[7];
  const float* ub1 = (const float*)d_in[8];
  const float* uw2 = (const float*)d_in[9];
  const float* ub2 = (const float*)d_in[10];
  const float* uw3 = (const float*)d_in[11];
  const float* ub3 = (const float*)d_in[12];
  float* out = (float*)d_out;

  char* ws = (char*)d_ws;
  u16*   xb   = (u16*)(ws + OFF_XB);
  u16*   H0   = (u16*)(ws + OFF_H0);
  u16*   H1   = (u16*)(ws + OFF_H1);
  u16*   W0T  = (u16*)(ws + OFF_W0T);
  u16*   W1T  = (u16*)(ws + OFF_W1T);
  u16*   W2T  = (u16*)(ws + OFF_W2T);
  u16*   uw2t = (u16*)(ws + OFF_UW2T);
  u16*   uw3t = (u16*)(ws + OFF_UW3T);
  float* cb   = (float*)(ws + OFF_CB);
  float* part = (float*)(ws + OFF_PART);

  k_convert<<<4481, 256, 0, stream>>>(x, uw2, uw3, b2, ub3, xb, uw2t, uw3t, cb);
  k_transpose<<<1312, 256, 0, stream>>>(W0, W1, W2, W0T, W1T, W2T);
  k_gemm<<<1024, 256, 0, stream>>>(xb, W0T, b0, H0, BATCH, HID, NINP);
  k_gemm<<<1024, 256, 0, stream>>>(H0, W1T, b1, H1, BATCH, HID, HID);
  k_uni<<<1024, 256, 0, stream>>>(x, uw1, ub1, uw2t, ub2, uw3t, H1, W2T, part);
  k_reduce<<<256, 256, 0, stream>>>(part, cb, out);
}